// Round 8
// baseline (180.219 us; speedup 1.0000x reference)
//
#include <hip/hip_runtime.h>
#include <hip/hip_bf16.h>

typedef short short8 __attribute__((ext_vector_type(8)));
typedef float floatx4 __attribute__((ext_vector_type(4)));
typedef unsigned short ushort_t;
typedef unsigned int uint32;

#define H 320
#define W 320
#define CG 16
#define NCH 64
#define HW (H * W)
#define HALFW 160

__device__ __forceinline__ ushort_t f2bf(float f) {
  unsigned u = __float_as_uint(f);
  return (ushort_t)((u + 0x7FFFu + ((u >> 16) & 1u)) >> 16);  // RNE (weights only)
}

// async DMA global->LDS, 4B per lane: LDS dest = base + lane*4 (linear),
// global source is PER-LANE (gather) -> does the [col][ic] transpose for free.
__device__ __forceinline__ void gld(const float* g, float* l) {
  __builtin_amdgcn_global_load_lds((const __attribute__((address_space(1))) void*)g,
                                   (__attribute__((address_space(3))) void*)l, 4, 0, 0);
}

// Block: 256 thr = 4 waves; ring-6 fp32 LDS tile [slot][col WH4][16 ic].
// Per task: each wave DMAs ONE new row (49 dword-DMAs), vmcnt(0)+barrier, compute.
template<int G>
__device__ __forceinline__ void conv_group(
    const float* __restrict__ x, const float* __restrict__ wgt,
    const float* __restrict__ bias, float* __restrict__ out,
    float* ldsf, const float* zp, int bx) {
  constexpr int DIL = (G == 0) ? 1 : (G == 1) ? 6 : (G == 2) ? 12 : 18;
  constexpr int WH4 = (160 + 2 * DIL + 3) & ~3;  // 164/172/184/196
  constexpr int NI  = WH4 / 4;                   // DMA instrs per row (41..49)
  constexpr int SS  = WH4 * 16;                  // floats per ring slot
  constexpr int WKS = 16 * DIL;                  // walks per group
  constexpr int RPW = (H + DIL - 1) / DIL;
  constexpr int Q   = (RPW + 3) / 4;             // 80/14/7/5
  constexpr int L   = (G == 0) ? 4 : (G == 1) ? 7 : Q;  // tasks per block

  const int tid  = threadIdx.x;
  const int lane = tid & 63;
  const int wv   = tid >> 6;

  // ---- weight A-fragment table (built in tile LDS, then overwritten) ----
  uint32* swt32 = (uint32*)ldsf;
#pragma unroll
  for (int k = 0; k < 5; ++k) {
    const int s = tid + k * 256;
    const int jp = s & 3, oc = (s >> 2) & 15, zt = (s >> 6) & 3, t = s >> 8;
    const int tp = 2 * t + (zt >> 1);
    uint32 pk = 0;
    if (tp < 9) {
      const float* wp = wgt + ((size_t)(G * CG + oc) * CG + (zt & 1) * 8 + 2 * jp) * 9 + tp;
      pk = (uint32)f2bf(wp[0]) | ((uint32)f2bf(wp[9]) << 16);
    }
    swt32[s] = pk;
  }
  __syncthreads();
  const int pxl = lane & 15, z = lane >> 4, icq = z & 1, zh = z >> 1;
  short8 aw[5];
  const ushort_t* swt = (const ushort_t*)ldsf;
#pragma unroll
  for (int t = 0; t < 5; ++t) aw[t] = *(const short8*)&swt[((t * 4 + z) * 16 + pxl) * 8];
  float bv[4];
#pragma unroll
  for (int rg = 0; rg < 4; ++rg) bv[rg] = bias[G * CG + z * 4 + rg];
  __syncthreads();                                // table read done; tile free for DMA

  // ---- decode (walk, chunk) ----
  const int walk  = bx % WKS;
  const int chunk = bx / WKS;
  const int r  = walk % DIL;
  const int wb = ((walk / DIL) & 1) * HALFW;
  const int b  = walk / (2 * DIL);
  const int q0 = chunk * L;
  const int qend = (q0 + L < Q) ? q0 + L : Q;

  const float* xg = x + (size_t)(b * NCH + G * CG) * HW;
  const int ic  = lane & 15;        // DMA: lane -> fixed input channel
  const int zz4 = lane >> 4;        // DMA: lane -> col within quad
  const int iLo = (wb == 0) ? (DIL + 3) >> 2 : 0;
  const int iHiT = ((W - 4 - wb + DIL) >> 2) + 1;
  const int iHi = iHiT < NI ? iHiT : NI;

  auto STAGE = [&](int rho, float* dst) {
    const int yy = rho * DIL + r;
    if (yy < 0 || yy >= H) {                      // whole row zero-pads
      const float* s0 = zp + lane;
#pragma unroll 1
      for (int i = 0; i < NI; ++i) gld((float*)s0, dst + i * 64);
      return;
    }
    const float* rowb = xg + (size_t)ic * HW + (size_t)yy * W;
    const int g0 = wb - DIL + zz4;                // lane's first global col
#pragma unroll 1
    for (int i = 0; i < iLo; ++i) {               // left edge: select zero page
      const int gc = g0 + 4 * i;
      const float* s = ((unsigned)gc < (unsigned)W) ? rowb + gc : zp + lane;
      gld((float*)s, dst + i * 64);
    }
    const float* sf = rowb + g0;
#pragma unroll 1
    for (int i = iLo; i < iHi; ++i)               // middle: pure pointer walk
      gld((float*)(sf + 4 * i), dst + i * 64);
#pragma unroll 1
    for (int i = iHi; i < NI; ++i) {              // right edge
      const int gc = g0 + 4 * i;
      const float* s = ((unsigned)gc < (unsigned)W) ? rowb + gc : zp + lane;
      gld((float*)s, dst + i * 64);
    }
  };

  // ---- prologue: DMA 6 rows ----
  {
    const int base = 4 * q0 - 1;
#pragma unroll
    for (int j0 = 0; j0 < 2; ++j0) {
      const int j = wv + j0 * 4;
      if (j < 6) {
        const int rho = base + j;
        STAGE(rho, ldsf + ((rho + 6) % 6) * SS);
      }
    }
  }
  asm volatile("s_waitcnt vmcnt(0)" ::: "memory");
  __builtin_amdgcn_s_barrier();

  // ---- task loop ----
#pragma unroll 1
  for (int q = q0; q < qend; ++q) {
    const int y = (4 * q + wv) * DIL + r;
    if (y < H) {
      const int sb = (4 * q + 5 + wv) % 6;        // slot of row 4q-1+wv
      const float* rp[5];
#pragma unroll
      for (int t = 0; t < 5; ++t) {
        const int tp = 2 * t + zh;
        const int ky = tp < 9 ? tp / 3 : 0;
        const int kx = tp < 9 ? tp % 3 : 0;
        int s = sb + ky; s -= (s >= 6) ? 6 : 0;
        rp[t] = ldsf + s * SS + (size_t)(pxl + kx * DIL) * 16 + icq * 8;
      }
      float* outb = out + (size_t)(b * NCH + G * CG) * HW + (size_t)y * W + wb;
#pragma unroll 2
      for (int ti = 0; ti < 10; ++ti) {
        floatx4 acc = {0.f, 0.f, 0.f, 0.f};
#pragma unroll
        for (int t = 0; t < 5; ++t) {
          const float4* fp = (const float4*)(rp[t] + ti * 256);
          const float4 lo = fp[0], hi = fp[1];    // 8 ic fp32, 2x ds_read_b128
          __hip_bfloat162 h0 = __float22bfloat162_rn(make_float2(lo.x, lo.y));
          __hip_bfloat162 h1 = __float22bfloat162_rn(make_float2(lo.z, lo.w));
          __hip_bfloat162 h2 = __float22bfloat162_rn(make_float2(hi.x, hi.y));
          __hip_bfloat162 h3 = __float22bfloat162_rn(make_float2(hi.z, hi.w));
          union { uint32 u[4]; short8 s8; } bu;
          bu.u[0] = *(const uint32*)&h0; bu.u[1] = *(const uint32*)&h1;
          bu.u[2] = *(const uint32*)&h2; bu.u[3] = *(const uint32*)&h3;
          acc = __builtin_amdgcn_mfma_f32_16x16x32_bf16(aw[t], bu.s8, acc, 0, 0, 0);
        }
        const int pxg = ti * 16 + pxl;
#pragma unroll
        for (int rg = 0; rg < 4; ++rg)            // C/D: col=lane&15, row=4z+rg
          outb[(size_t)(z * 4 + rg) * HW + pxg] = acc[rg] + bv[rg];
      }
    }
    if (q + 1 < qend) {
      __builtin_amdgcn_s_barrier();               // all waves done reading tile
      const int rho = 4 * q + 5 + wv;             // each wave DMAs one new row
      STAGE(rho, ldsf + (rho % 6) * SS);
      asm volatile("s_waitcnt vmcnt(0)" ::: "memory");
      __builtin_amdgcn_s_barrier();               // new rows landed
    }
  }
}

extern "C" __global__ void __launch_bounds__(256, 2) conv_all(
    const float* __restrict__ x, const float* __restrict__ wgt,
    const float* __restrict__ bias, float* __restrict__ out,
    const float* __restrict__ zp) {
  extern __shared__ float ldsf[];
  const int bid = blockIdx.x;
  if (bid < 288)      conv_group<3>(x, wgt, bias, out, ldsf, zp, bid);        // 288
  else if (bid < 480) conv_group<2>(x, wgt, bias, out, ldsf, zp, bid - 288);  // 192
  else if (bid < 672) conv_group<1>(x, wgt, bias, out, ldsf, zp, bid - 480);  // 192 (2 chunks)
  else                conv_group<0>(x, wgt, bias, out, ldsf, zp, bid - 672);  // 320 (20 chunks)
}

extern "C" void kernel_launch(void* const* d_in, const int* in_sizes, int n_in,
                              void* d_out, int out_size, void* d_ws, size_t ws_size,
                              hipStream_t stream) {
  const float* x    = (const float*)d_in[0];
  const float* wgt  = (const float*)d_in[1];
  const float* bias = (const float*)d_in[2];
  float* out        = (float*)d_out;

  hipMemsetAsync(d_ws, 0, 4096, stream);          // zero page for OOB DMA lanes
  // dynamic LDS = G3 ring: 6 * 196 * 16 * 4 = 75264 B -> 2 blocks/CU
  const size_t lds_bytes = 6 * 196 * 16 * sizeof(float);
  conv_all<<<dim3(992), dim3(256), lds_bytes, stream>>>(x, wgt, bias, out,
                                                        (const float*)d_ws);
}

// Round 9
// 112.677 us; speedup vs baseline: 1.5994x; 1.5994x over previous
//
#include <hip/hip_runtime.h>
#include <hip/hip_bf16.h>

typedef short short8 __attribute__((ext_vector_type(8)));
typedef short short4_t __attribute__((ext_vector_type(4)));
typedef float floatx4 __attribute__((ext_vector_type(4)));
typedef unsigned short ushort_t;
typedef unsigned int uint32;

#define H 320
#define W 320
#define CG 16
#define NCH 64
#define CGP 20       // ushorts per LDS col (40B): conflict-free b64 frag reads (measured 0)
#define HALFW 160

__device__ __forceinline__ ushort_t f2bf(float f) {
  unsigned u = __float_as_uint(f);
  return (ushort_t)((u + 0x7FFFu + ((u >> 16) & 1u)) >> 16);  // RNE (weights only)
}

// LDS-only barrier: does NOT drain vmcnt -> global loads/stores stay in flight.
__device__ __forceinline__ void barrier_lgkm() {
  asm volatile("s_waitcnt lgkmcnt(0)" ::: "memory");
  __builtin_amdgcn_s_barrier();
}

// Block: 256 thr = 4 waves. Walks q upward within one (r, wb, b) column strip;
// ring-6 LDS row buffer: steady-state stages 4 new rows per 4 output rows.
// Task loop body is STRAIGHT-LINE (final iter peeled) so the compiler cannot
// merge/sink the prefetch block into the post-barrier cvt block.
template<int G>
__device__ __forceinline__ void conv_group(
    const float* __restrict__ x, const float* __restrict__ wgt,
    const float* __restrict__ bias, float* __restrict__ out,
    ushort_t* lds, int bx) {
  constexpr int DIL   = (G == 0) ? 1 : (G == 1) ? 6 : (G == 2) ? 12 : 18;
  constexpr int KOFF  = DIL & 1;
  constexpr int SHIFT = DIL + KOFF;              // lds col c <-> global col wb + c - SHIFT
  constexpr int WH    = (HALFW + 2 * DIL + KOFF + 1) & ~1;  // 164/172/184/196
  constexpr int NP    = (WH + 63) / 64;          // 3/3/3/4
  constexpr int WKS   = 16 * DIL;                // walks = DIL * 2(wb) * 8(b)
  constexpr int RPW   = (H + DIL - 1) / DIL;
  constexpr int Q     = (RPW + 3) / 4;           // 80/14/7/5 tasks per walk
  constexpr int CPW   = (G == 0) ? 12 : (G == 1) ? 2 : 1;
  constexpr int L     = (Q + CPW - 1) / CPW;     // 7/7/7/5 tasks per chunk

  const int tid = threadIdx.x;
  ushort_t* tile = lds;                          // [6][WH][CGP]
  ushort_t* swt  = lds + 6 * WH * CGP;           // [5][4][16][8] A-frag table
  uint32* swt32  = (uint32*)swt;

  // ---- weight A-fragment table (once per block) ----
#pragma unroll
  for (int k = 0; k < 5; ++k) {
    const int s = tid + k * 256;
    const int jp = s & 3, oc = (s >> 2) & 15, zz = (s >> 6) & 3, t = s >> 8;
    const int tp = 2 * t + (zz >> 1);
    uint32 pk = 0;
    if (tp < 9) {
      const float* wp = wgt + ((size_t)(G * CG + oc) * CG + (zz & 1) * 8 + 2 * jp) * 9 + tp;
      pk = (uint32)f2bf(wp[0]) | ((uint32)f2bf(wp[9]) << 16);
    }
    swt32[s] = pk;
  }
  __syncthreads();

  const int lane = tid & 63;
  const int wv   = tid >> 6;
  const int z = lane >> 4, icq = z & 1, pxl = lane & 15;
  short8 aw[5];
#pragma unroll
  for (int t = 0; t < 5; ++t) aw[t] = *(const short8*)&swt[((t * 4 + z) * 16 + (lane & 15)) * 8];
  float bv[4];
#pragma unroll
  for (int rg = 0; rg < 4; ++rg) bv[rg] = bias[G * CG + z * 4 + rg];

  // ---- decode block -> (walk, chunk) ----
  const int walk  = bx % WKS;
  const int chunk = bx / WKS;
  const int r  = walk % DIL;
  const int wb = ((walk / DIL) & 1) * HALFW;
  const int b  = walk / (2 * DIL);
  const int q0 = chunk * L;
  const int qend = (q0 + L < Q) ? q0 + L : Q;

  // ---- staging constants: thread = (col = lane, ch-quad = wv) ----
  bool zm[NP]; bool inb[NP]; int gofs[NP];
#pragma unroll
  for (int p = 0; p < NP; ++p) {
    const int c = 64 * p + lane;
    inb[p] = (c < WH);
    const int gc = wb + c - SHIFT;
    zm[p] = inb[p] & (gc >= 0) & (gc < W);
    gofs[p] = gc < 0 ? 0 : (gc >= W ? W - 1 : gc);
  }
  const float* chb = x + (size_t)(b * NCH + G * CG + 4 * wv) * (H * W);

  auto LOADR = [&](int rho, float (&rg)[NP][4]) {
    const int yy = rho * DIL + r;
    const int yyc = yy < 0 ? 0 : (yy >= H ? H - 1 : yy);
    const float* rp = chb + (size_t)yyc * W;
#pragma unroll
    for (int p = 0; p < NP; ++p)
#pragma unroll
      for (int k = 0; k < 4; ++k)
        rg[p][k] = rp[(size_t)k * (H * W) + gofs[p]];   // 256B coalesced per inst
  };

  // Opaque touch: raw floats must be live HERE -> counted vmcnt lands after COMPUTE.
  auto KEEP = [&](float (&rg)[NP][4]) {
#pragma unroll
    for (int p = 0; p < NP; ++p)
      asm volatile("" : "+v"(rg[p][0]), "+v"(rg[p][1]), "+v"(rg[p][2]), "+v"(rg[p][3]));
  };

  auto CVTR = [&](int rho, int slot, float (&rg)[NP][4]) {
    const int yy = rho * DIL + r;
    const bool rv = (yy >= 0) & (yy < H);
#pragma unroll
    for (int p = 0; p < NP; ++p) {
      const bool m = rv & zm[p];
      const __hip_bfloat162 h01 = __float22bfloat162_rn(make_float2(rg[p][0], rg[p][1]));
      const __hip_bfloat162 h23 = __float22bfloat162_rn(make_float2(rg[p][2], rg[p][3]));
      uint2 pk;
      pk.x = m ? *(const uint32*)&h01 : 0u;
      pk.y = m ? *(const uint32*)&h23 : 0u;
      if (inb[p]) {
        const int c = 64 * p + lane;
        *(uint2*)&tile[(size_t)(slot * WH + c) * CGP + wv * 4] = pk;  // ds_write_b64
      }
    }
  };

  auto COMPUTE = [&](int q, int m6) {
    const int y = (4 * q + wv) * DIL + r;
    if (y >= H) return;
    const int zh = z >> 1;
    float* outb = out + (size_t)(b * NCH + G * CG) * (H * W) + (size_t)y * W + wb;
    const ushort_t* rowp[5];                 // statically indexed (unrolled t)
#pragma unroll
    for (int t = 0; t < 5; ++t) {
      const int tp = 2 * t + zh;
      const int ky = tp < 9 ? tp / 3 : 0;
      const int kx = tp < 9 ? tp - ky * 3 : 0;
      int s = m6 + wv + ky; s -= (s >= 6) ? 6 : 0;   // slot of row j = wv+ky
      rowp[t] = tile + (size_t)s * (WH * CGP) + (size_t)(pxl + kx * DIL + KOFF) * CGP + icq * 8;
    }
#pragma unroll 2
    for (int ti = 0; ti < HALFW / 16; ++ti) {
      floatx4 acc = {0.f, 0.f, 0.f, 0.f};
#pragma unroll
      for (int t = 0; t < 5; ++t) {
        const ushort_t* pf = rowp[t] + ti * 16 * CGP;
        const short4_t lo = *(const short4_t*)pf;
        const short4_t hi = *(const short4_t*)(pf + 4);
        const short8 bf = {lo[0], lo[1], lo[2], lo[3], hi[0], hi[1], hi[2], hi[3]};
        acc = __builtin_amdgcn_mfma_f32_16x16x32_bf16(aw[t], bf, acc, 0, 0, 0);
      }
      const int pxg = ti * 16 + pxl;
#pragma unroll
      for (int rg = 0; rg < 4; ++rg)
        outb[(size_t)(z * 4 + rg) * (H * W) + pxg] = acc[rg] + bv[rg];  // C/D: col=lane&15, row=4z+rg
    }
  };

  auto wrap6 = [](int v) { return v >= 6 ? v - 6 : v; };
  int m6 = (4 * q0 + 5) % 6;                 // slot of row rho = 4q-1 (ring-6)

  // ---- prologue: stage 6 rows (pairwise pipelined) ----
  {
    float ra[NP][4], rb[NP][4];
    LOADR(4 * q0 - 1, ra); LOADR(4 * q0 + 0, rb);
    CVTR(4 * q0 - 1, wrap6(m6 + 0), ra); CVTR(4 * q0 + 0, wrap6(m6 + 1), rb);
    LOADR(4 * q0 + 1, ra); LOADR(4 * q0 + 2, rb);
    CVTR(4 * q0 + 1, wrap6(m6 + 2), ra); CVTR(4 * q0 + 2, wrap6(m6 + 3), rb);
    LOADR(4 * q0 + 3, ra); LOADR(4 * q0 + 4, rb);
    CVTR(4 * q0 + 3, wrap6(m6 + 4), ra); CVTR(4 * q0 + 4, wrap6(m6 + 5), rb);
  }
  barrier_lgkm();

  // ---- task loop: straight-line body; final iteration peeled ----
#pragma unroll 1
  for (int q = q0; q < qend - 1; ++q) {
    float ra[NP][4], rb[NP][4], rc[NP][4], rd[NP][4];
    LOADR(4 * q + 5, ra); LOADR(4 * q + 6, rb);
    LOADR(4 * q + 7, rc); LOADR(4 * q + 8, rd);
    __builtin_amdgcn_sched_barrier(0);       // loads issue before COMPUTE
    COMPUTE(q, m6);                          // prefetch drains under this
    __builtin_amdgcn_sched_barrier(0);
    barrier_lgkm();                          // tile readers done (lgkm only)
    KEEP(ra); KEEP(rb); KEEP(rc); KEEP(rd);  // vmcnt wait lands HERE
    CVTR(4 * q + 5, m6,            ra);
    CVTR(4 * q + 6, wrap6(m6 + 1), rb);
    CVTR(4 * q + 7, wrap6(m6 + 2), rc);
    CVTR(4 * q + 8, wrap6(m6 + 3), rd);
    barrier_lgkm();                          // tile ready for next task
    m6 = wrap6(m6 + 4);
  }
  COMPUTE(qend - 1, m6);                     // epilogue: no staging
}

extern "C" __global__ void __launch_bounds__(256, 3) conv_all(
    const float* __restrict__ x, const float* __restrict__ wgt,
    const float* __restrict__ bias, float* __restrict__ out) {
  extern __shared__ ushort_t lds[];
  const int bid = blockIdx.x;
  if (bid < 288)      conv_group<3>(x, wgt, bias, out, lds, bid);        // 288 blocks
  else if (bid < 480) conv_group<2>(x, wgt, bias, out, lds, bid - 288);  // 192
  else if (bid < 672) conv_group<1>(x, wgt, bias, out, lds, bid - 480);  // 192
  else                conv_group<0>(x, wgt, bias, out, lds, bid - 672);  // 192
}

extern "C" void kernel_launch(void* const* d_in, const int* in_sizes, int n_in,
                              void* d_out, int out_size, void* d_ws, size_t ws_size,
                              hipStream_t stream) {
  const float* x    = (const float*)d_in[0];
  const float* wgt  = (const float*)d_in[1];
  const float* bias = (const float*)d_in[2];
  float* out        = (float*)d_out;

  // dynamic LDS (max over groups, G3): 6*196*20*2 + 5120 = 52160 B -> 3 blocks/CU
  const size_t lds_bytes = (size_t)(6 * 196 * CGP + 5 * 4 * 16 * 8) * 2;
  conv_all<<<dim3(864), dim3(256), lds_bytes, stream>>>(x, wgt, bias, out);
}